// Round 1
// baseline (57.387 us; speedup 1.0000x reference)
//
#include <hip/hip_runtime.h>
#include <hip/hip_bf16.h>

// Problem: B=32, C=256, H=W=512, labels in [0,150).
// counts[b] = #unique label values in label[b]; out = mean_b( lse(cls[b]) - cls[b][counts[b]] )

#define B_SAMPLES 32
#define C_CLASSES 256
#define N_PER_SAMPLE (512 * 512)
#define CHUNKS 64                       // blocks per sample
#define PER_CHUNK (N_PER_SAMPLE / CHUNKS)  // 4096 elements

// Kernel 1: build per-sample 256-bit presence bitmap (4 x u64 per sample).
__global__ __launch_bounds__(256) void count_bitmap_kernel(
    const int* __restrict__ label, unsigned long long* __restrict__ bitmap) {
    const int b = blockIdx.x / CHUNKS;
    const int chunk = blockIdx.x % CHUNKS;

    __shared__ int flag[C_CLASSES];
    flag[threadIdx.x] = 0;
    __syncthreads();

    const int4* p = reinterpret_cast<const int4*>(
        label + (long)b * N_PER_SAMPLE + (long)chunk * PER_CHUNK);
    // PER_CHUNK/4 = 1024 int4 across 256 threads -> 4 iterations
    #pragma unroll
    for (int i = 0; i < PER_CHUNK / 4 / 256; ++i) {
        int4 v = p[i * 256 + threadIdx.x];
        flag[v.x & 255] = 1;   // racy same-value stores: fine
        flag[v.y & 255] = 1;
        flag[v.z & 255] = 1;
        flag[v.w & 255] = 1;
    }
    __syncthreads();

    // 256 threads = 4 waves of 64; each wave ballots 64 flags into one u64 word.
    unsigned long long m = __ballot(flag[threadIdx.x] != 0);
    const int wave = threadIdx.x >> 6;
    if ((threadIdx.x & 63) == 0 && m != 0ull) {
        atomicOr(&bitmap[b * 4 + wave], m);
    }
}

// Kernel 2: counts = popcount(bitmap); CE = mean_b( lse(row_b) - row_b[count_b] )
__global__ __launch_bounds__(256) void ce_kernel(
    const float* __restrict__ cls,
    const unsigned long long* __restrict__ bitmap,
    float* __restrict__ out) {
    const int t = threadIdx.x;
    const int wave = t >> 6;
    const int lane = t & 63;

    __shared__ float red[8];
    float nll_sum = 0.0f;

    for (int b = 0; b < B_SAMPLES; ++b) {
        const float x = cls[b * C_CLASSES + t];

        // block max
        float m = x;
        #pragma unroll
        for (int off = 32; off > 0; off >>= 1) m = fmaxf(m, __shfl_xor(m, off));
        if (lane == 0) red[wave] = m;
        __syncthreads();
        const float mmax = fmaxf(fmaxf(red[0], red[1]), fmaxf(red[2], red[3]));

        // block sum of exp
        float e = expf(x - mmax);
        #pragma unroll
        for (int off = 32; off > 0; off >>= 1) e += __shfl_xor(e, off);
        if (lane == 0) red[4 + wave] = e;
        __syncthreads();
        const float total = red[4] + red[5] + red[6] + red[7];
        const float lse = mmax + logf(total);

        if (t == 0) {
            int cnt = 0;
            #pragma unroll
            for (int w = 0; w < 4; ++w) cnt += __popcll(bitmap[b * 4 + w]);
            nll_sum += lse - cls[b * C_CLASSES + cnt];
        }
        __syncthreads();  // protect red[] before next iteration
    }

    if (t == 0) out[0] = nll_sum / (float)B_SAMPLES;
}

extern "C" void kernel_launch(void* const* d_in, const int* in_sizes, int n_in,
                              void* d_out, int out_size, void* d_ws, size_t ws_size,
                              hipStream_t stream) {
    const float* cls = (const float*)d_in[0];
    const int* label = (const int*)d_in[1];
    float* out = (float*)d_out;
    unsigned long long* bitmap = (unsigned long long*)d_ws;  // 32 * 4 * 8 = 1 KiB

    hipMemsetAsync(bitmap, 0, B_SAMPLES * 4 * sizeof(unsigned long long), stream);

    count_bitmap_kernel<<<B_SAMPLES * CHUNKS, 256, 0, stream>>>(label, bitmap);
    ce_kernel<<<1, 256, 0, stream>>>(cls, bitmap, out);
}

// Round 2
// 19.992 us; speedup vs baseline: 2.8705x; 2.8705x over previous
//
#include <hip/hip_runtime.h>
#include <hip/hip_bf16.h>

// Problem: B=32, C=256, H=W=512, labels in [0,150).
// counts[b] = #unique label values in label[b]; out = mean_b( lse(cls[b]) - cls[b][counts[b]] )

#define B_SAMPLES 32
#define C_CLASSES 256
#define N_PER_SAMPLE (512 * 512)
#define CHUNKS 64                          // blocks per sample
#define PER_CHUNK (N_PER_SAMPLE / CHUNKS)  // 4096 elements

// Kernel 1: each block computes a 256-bit presence mask for its chunk and
// writes it to its OWN ws slot (no atomics, no init required).
// ws layout: u64 masks[B_SAMPLES * CHUNKS][4]
__global__ __launch_bounds__(256) void count_bitmap_kernel(
    const int* __restrict__ label, unsigned long long* __restrict__ masks) {
    const int b = blockIdx.x / CHUNKS;
    const int chunk = blockIdx.x % CHUNKS;

    __shared__ int flag[C_CLASSES];
    flag[threadIdx.x] = 0;
    __syncthreads();

    const int4* p = reinterpret_cast<const int4*>(
        label + (long)b * N_PER_SAMPLE + (long)chunk * PER_CHUNK);
    #pragma unroll
    for (int i = 0; i < PER_CHUNK / 4 / 256; ++i) {   // 4 iterations
        int4 v = p[i * 256 + threadIdx.x];
        flag[v.x & 255] = 1;   // racy same-value stores: fine
        flag[v.y & 255] = 1;
        flag[v.z & 255] = 1;
        flag[v.w & 255] = 1;
    }
    __syncthreads();

    unsigned long long m = __ballot(flag[threadIdx.x] != 0);
    const int wave = threadIdx.x >> 6;
    if ((threadIdx.x & 63) == 0) {
        masks[(unsigned)blockIdx.x * 4 + wave] = m;   // unconditional: overwrites poison
    }
}

// Kernel 2: OR-reduce chunk masks -> counts; CE fully in registers.
__global__ __launch_bounds__(256) void ce_kernel(
    const float* __restrict__ cls,
    const unsigned long long* __restrict__ masks,
    float* __restrict__ out) {
    const int t = threadIdx.x;

    __shared__ int cnt_sh[B_SAMPLES];
    __shared__ float partial[4];

    // ---- Phase A: 128 threads, one (sample, word) each ----
    if (t < 128) {
        const int b = t >> 2;
        const int word = t & 3;
        unsigned long long m = 0ull;
        #pragma unroll 8
        for (int c = 0; c < CHUNKS; ++c) {
            m |= masks[(unsigned)(b * CHUNKS + c) * 4 + word];
        }
        int p = __popcll(m);
        p += __shfl_xor(p, 1);   // sum popcounts across the 4 words (lanes 4k..4k+3)
        p += __shfl_xor(p, 2);
        if (word == 0) cnt_sh[b] = p;
    }
    __syncthreads();

    // ---- Phase B: wave w handles samples [8w, 8w+8); lane l holds float4 of row ----
    const int w = t >> 6;
    const int l = t & 63;

    float4 v[8];
    #pragma unroll
    for (int i = 0; i < 8; ++i) {   // issue all loads up front; latencies overlap
        const int b = w * 8 + i;
        v[i] = reinterpret_cast<const float4*>(cls)[b * 64 + l];
    }

    float nll = 0.0f;
    #pragma unroll
    for (int i = 0; i < 8; ++i) {
        const int b = w * 8 + i;
        const float4 x = v[i];
        float m = fmaxf(fmaxf(x.x, x.y), fmaxf(x.z, x.w));
        #pragma unroll
        for (int off = 32; off > 0; off >>= 1) m = fmaxf(m, __shfl_xor(m, off));
        float e = expf(x.x - m) + expf(x.y - m) + expf(x.z - m) + expf(x.w - m);
        #pragma unroll
        for (int off = 32; off > 0; off >>= 1) e += __shfl_xor(e, off);
        const float lse = m + logf(e);

        const int cnt = cnt_sh[b];            // wave-uniform
        const int comp = cnt & 3;
        const float cand = (comp == 0) ? x.x : (comp == 1) ? x.y
                         : (comp == 2) ? x.z : x.w;
        const float target = __shfl(cand, cnt >> 2);
        nll += lse - target;
    }

    if (l == 0) partial[w] = nll;
    __syncthreads();
    if (t == 0) out[0] = (partial[0] + partial[1] + partial[2] + partial[3]) / (float)B_SAMPLES;
}

extern "C" void kernel_launch(void* const* d_in, const int* in_sizes, int n_in,
                              void* d_out, int out_size, void* d_ws, size_t ws_size,
                              hipStream_t stream) {
    const float* cls = (const float*)d_in[0];
    const int* label = (const int*)d_in[1];
    float* out = (float*)d_out;
    unsigned long long* masks = (unsigned long long*)d_ws;  // 2048 * 4 * 8 = 64 KiB

    count_bitmap_kernel<<<B_SAMPLES * CHUNKS, 256, 0, stream>>>(label, masks);
    ce_kernel<<<1, 256, 0, stream>>>(cls, masks, out);
}

// Round 4
// 18.150 us; speedup vs baseline: 3.1618x; 1.1015x over previous
//
#include <hip/hip_runtime.h>
#include <hip/hip_bf16.h>

// Problem: B=32, C=256, H=W=512, labels in [0,150).
// counts[b] = #unique label values in label[b]; out = mean_b( lse(cls[b]) - cls[b][counts[b]] )

#define B_SAMPLES 32
#define C_CLASSES 256
#define N_PER_SAMPLE (512 * 512)
#define CHUNKS 64                          // blocks per sample
#define PER_CHUNK (N_PER_SAMPLE / CHUNKS)  // 4096 elements

// Kernel 1: per-chunk 256-bit presence mask -> own ws slot (no atomics, no init).
// ws layout: u64 masks[B_SAMPLES * CHUNKS][4]
__global__ __launch_bounds__(256) void count_bitmap_kernel(
    const int* __restrict__ label, unsigned long long* __restrict__ masks) {
    const int b = blockIdx.x / CHUNKS;
    const int chunk = blockIdx.x % CHUNKS;
    const int t = threadIdx.x;

    __shared__ int flag[C_CLASSES];
    flag[t] = 0;
    __syncthreads();

    const int4* p = reinterpret_cast<const int4*>(
        label + (long)b * N_PER_SAMPLE + (long)chunk * PER_CHUNK);
    // Issue all 4 dwordx4 loads before any LDS store (keep them in flight).
    const int4 v0 = p[0 * 256 + t];
    const int4 v1 = p[1 * 256 + t];
    const int4 v2 = p[2 * 256 + t];
    const int4 v3 = p[3 * 256 + t];

    flag[v0.x & 255] = 1; flag[v0.y & 255] = 1; flag[v0.z & 255] = 1; flag[v0.w & 255] = 1;
    flag[v1.x & 255] = 1; flag[v1.y & 255] = 1; flag[v1.z & 255] = 1; flag[v1.w & 255] = 1;
    flag[v2.x & 255] = 1; flag[v2.y & 255] = 1; flag[v2.z & 255] = 1; flag[v2.w & 255] = 1;
    flag[v3.x & 255] = 1; flag[v3.y & 255] = 1; flag[v3.z & 255] = 1; flag[v3.w & 255] = 1;
    __syncthreads();

    unsigned long long m = __ballot(flag[t] != 0);
    if ((t & 63) == 0) {
        masks[(unsigned)blockIdx.x * 4 + (t >> 6)] = m;  // unconditional: overwrites poison
    }
}

// Kernel 2: OR-reduce chunk masks -> counts; CE in registers.
__global__ __launch_bounds__(256) void ce_kernel(
    const float* __restrict__ cls,
    const unsigned long long* __restrict__ masks,
    float* __restrict__ out) {
    const int t = threadIdx.x;
    const int w = t >> 6;
    const int l = t & 63;

    __shared__ int cnt_sh[B_SAMPLES];
    __shared__ float partial[4];

    // ---- Issue phase-B cls loads FIRST so they overlap phase A's mask loads ----
    float4 v[8];
    #pragma unroll
    for (int i = 0; i < 8; ++i) {
        const int b = w * 8 + i;
        v[i] = reinterpret_cast<const float4*>(cls)[b * 64 + l];
    }

    // ---- Phase A: 256 threads; 2 threads per (sample, word), 32 chunks each ----
    // Thread t: sample b = t>>3, word = (t>>1)&3, sub-half = t&1.
    {
        const int item = t >> 1;           // 0..127
        const int sub  = t & 1;            // which half of the 64 chunks
        const int b    = item >> 2;        // 0..31
        const int word = item & 3;         // 0..3
        const unsigned long long* base =
            masks + ((unsigned)(b * CHUNKS + sub * 32)) * 4 + word;

        unsigned long long acc = 0ull;
        #pragma unroll
        for (int jj = 0; jj < 4; ++jj) {   // 4 batches of 8 independent loads
            const unsigned long long x0 = base[(jj * 8 + 0) * 4];
            const unsigned long long x1 = base[(jj * 8 + 1) * 4];
            const unsigned long long x2 = base[(jj * 8 + 2) * 4];
            const unsigned long long x3 = base[(jj * 8 + 3) * 4];
            const unsigned long long x4 = base[(jj * 8 + 4) * 4];
            const unsigned long long x5 = base[(jj * 8 + 5) * 4];
            const unsigned long long x6 = base[(jj * 8 + 6) * 4];
            const unsigned long long x7 = base[(jj * 8 + 7) * 4];
            acc |= ((x0 | x1) | (x2 | x3)) | ((x4 | x5) | (x6 | x7));
        }

        // MERGE the two sub-half ORs BEFORE popcount (union != popcount sum!)
        acc |= __shfl_xor(acc, 1);
        int p = __popcll(acc);
        // Words are disjoint 64-bit ranges -> popcount sums are valid across words.
        p += __shfl_xor(p, 2);   // combine words 0/1, 2/3
        p += __shfl_xor(p, 4);   // combine word pairs
        if ((t & 7) == 0) cnt_sh[t >> 3] = p;
    }
    __syncthreads();

    // ---- Phase B: wave w handles samples [8w, 8w+8) ----
    float nll = 0.0f;
    #pragma unroll
    for (int i = 0; i < 8; ++i) {
        const int b = w * 8 + i;
        const float4 x = v[i];
        float m = fmaxf(fmaxf(x.x, x.y), fmaxf(x.z, x.w));
        #pragma unroll
        for (int off = 32; off > 0; off >>= 1) m = fmaxf(m, __shfl_xor(m, off));
        float e = expf(x.x - m) + expf(x.y - m) + expf(x.z - m) + expf(x.w - m);
        #pragma unroll
        for (int off = 32; off > 0; off >>= 1) e += __shfl_xor(e, off);
        const float lse = m + logf(e);

        const int cnt = cnt_sh[b];            // wave-uniform
        const int comp = cnt & 3;
        const float cand = (comp == 0) ? x.x : (comp == 1) ? x.y
                         : (comp == 2) ? x.z : x.w;
        const float target = __shfl(cand, cnt >> 2);
        nll += lse - target;
    }

    if (l == 0) partial[w] = nll;
    __syncthreads();
    if (t == 0) out[0] = (partial[0] + partial[1] + partial[2] + partial[3]) / (float)B_SAMPLES;
}

extern "C" void kernel_launch(void* const* d_in, const int* in_sizes, int n_in,
                              void* d_out, int out_size, void* d_ws, size_t ws_size,
                              hipStream_t stream) {
    const float* cls = (const float*)d_in[0];
    const int* label = (const int*)d_in[1];
    float* out = (float*)d_out;
    unsigned long long* masks = (unsigned long long*)d_ws;  // 2048 * 4 * 8 = 64 KiB

    count_bitmap_kernel<<<B_SAMPLES * CHUNKS, 256, 0, stream>>>(label, masks);
    ce_kernel<<<1, 256, 0, stream>>>(cls, masks, out);
}